// Round 2
// baseline (638.260 us; speedup 1.0000x reference)
//
#include <hip/hip_runtime.h>
#include <math.h>

// Problem constants
#define kH  1024
#define kB  64
#define kS  256
#define kV  10000
#define kH3 3072

// ---------------- helpers ----------------
__device__ __forceinline__ float warp_sum(float v) {
#pragma unroll
  for (int off = 32; off > 0; off >>= 1) v += __shfl_down(v, off, 64);
  return v;  // valid on lane 0
}
__device__ __forceinline__ float warp_max_all(float v) {
#pragma unroll
  for (int off = 32; off > 0; off >>= 1) v = fmaxf(v, __shfl_xor(v, off, 64));
  return v;
}
__device__ __forceinline__ float warp_sum_all(float v) {
#pragma unroll
  for (int off = 32; off > 0; off >>= 1) v += __shfl_xor(v, off, 64);
  return v;
}
__device__ __forceinline__ float sigmoidf_(float x) {
  return __fdividef(1.0f, 1.0f + __expf(-x));
}
// fast tanh via exp(-2|x|): no overflow, ~8 instrs instead of libm call.
// On lane0's serial GRU chain 2x per step.
__device__ __forceinline__ float tanhf_(float x) {
  const float t = __expf(-2.0f * fabsf(x));
  const float r = __fdividef(1.0f - t, 1.0f + t);
  return copysignf(r, x);
}

// ---------------- GI = emb[seq] @ W_ih^T + b_ih  (64 x 3072) ----------------
// grid 768 x 256: one wave per output row r (3072 rows), loop over t=0..63.
__global__ __launch_bounds__(256) void k_gi(const int* __restrict__ seq,
    const float* __restrict__ emb, const float* __restrict__ W_ih,
    const float* __restrict__ b_ih, float* __restrict__ GI) {
  const int lane = threadIdx.x & 63;
  const int r = blockIdx.x * 4 + (threadIdx.x >> 6);
  const float4* wp = (const float4*)(W_ih + (size_t)r * kH) + lane * 4;
  const float4 w0 = wp[0], w1 = wp[1], w2 = wp[2], w3 = wp[3];
  const float br = b_ih[r];
  for (int t = 0; t < kB; ++t) {
    const int tok = seq[t];
    const float4* xp = (const float4*)(emb + (size_t)tok * kH) + lane * 4;
    const float4 x0 = xp[0], x1 = xp[1], x2 = xp[2], x3 = xp[3];
    float acc = w0.x*x0.x + w0.y*x0.y + w0.z*x0.z + w0.w*x0.w;
    acc += w1.x*x1.x + w1.y*x1.y + w1.z*x1.z + w1.w*x1.w;
    acc += w2.x*x2.x + w2.y*x2.y + w2.z*x2.z + w2.w*x2.w;
    acc += w3.x*x3.x + w3.y*x3.y + w3.z*x3.z + w3.w*x3.w;
    acc = warp_sum(acc);
    if (lane == 0) GI[(size_t)t * kH3 + r] = acc + br;
  }
}

// ---------------- Persistent GRU scan (64 sequential steps) ----------------
// grid 64 x 512 (all resident). Block bid owns h[16*bid..16*bid+15]; wave w
// owns pair j = 16*bid + 2w. Handshake: relaxed agent-scope u64 atomics
// carrying (tag = t+1, float bits); 64-bit single-location atomicity means
// no fences needed. ws poison 0xAAAAAAAA never matches tags 1..64.
//
// R2 changes vs R1:
//  * asm "+v" pin on every wv element: R1 proved launch_bounds alone does
//    NOT make the compiler keep the 96 weights resident (VGPR stayed 76 ->
//    96 L2 re-loads per sequential step). The asm output is opaque, so
//    rematerialization is impossible; regalloc must keep them in VGPRs
//    (budget 256 via launch_bounds(512,2)).
//  * libm tanhf -> exp-based fast tanh on lane0's serial chain.
__global__ __launch_bounds__(512, 2) void k_gru(const float* __restrict__ h0,
    const float* __restrict__ W_hh, const float* __restrict__ b_hh,
    const float* __restrict__ GI, float* __restrict__ rnn,
    unsigned long long* __restrict__ step) {
  __shared__ float hs[2][kH];
  const int tid  = threadIdx.x;
  const int lane = tid & 63;
  const int w    = tid >> 6;           // 0..7
  const int bid  = blockIdx.x;         // 0..63
  const int j    = bid * 16 + 2 * w;   // h-pair base

  // Weights in registers, laid out to match hx[u] = h[u*64 + lane]:
  // wv[q][u] = W_hh[rows[q]][u*64 + lane]  (coalesced load per (q,u))
  float wv[6][16];
  {
    const int rows[6] = { j, j + 1, kH + j, kH + j + 1, 2 * kH + j, 2 * kH + j + 1 };
#pragma unroll
    for (int q = 0; q < 6; ++q) {
      const float* base = W_hh + (size_t)rows[q] * kH + lane;
#pragma unroll
      for (int u = 0; u < 16; ++u) wv[q][u] = base[u * 64];
    }
  }
  // Force true register residency across the t-loop (see header comment).
#pragma unroll
  for (int q = 0; q < 6; ++q)
#pragma unroll
    for (int u = 0; u < 16; ++u)
      asm volatile("" : "+v"(wv[q][u]));

  const float2 bhr = *(const float2*)(b_hh + j);
  const float2 bhz = *(const float2*)(b_hh + kH + j);
  const float2 bhn = *(const float2*)(b_hh + 2 * kH + j);

  for (int t = 0; t < kB; ++t) {
    // ---- prefetch GI[t] (h-independent) so its latency hides under the
    //      poll. All lanes load (HW broadcasts); only lane0 consumes.
    float2 gir = *(const float2*)(GI + (size_t)t * kH3 + j);
    float2 giz = *(const float2*)(GI + (size_t)t * kH3 + kH + j);
    float2 gin = *(const float2*)(GI + (size_t)t * kH3 + 2 * kH + j);
    asm volatile("" :: "v"(gir.x), "v"(gir.y), "v"(giz.x), "v"(giz.y),
                       "v"(gin.x), "v"(gin.y));

    float* hb = hs[t & 1];
    // ---- stage h_prev into LDS (2 slots per thread) ----
    if (t == 0) {
      ((float2*)hb)[tid] = ((const float2*)h0)[tid];
    } else {
      const unsigned long long* sb = step + (size_t)(t - 1) * kH;
      const int i0 = tid * 2, i1 = i0 + 1;
      const unsigned want = (unsigned)t;  // producer of step t-1 wrote tag t
      bool d0 = false, d1 = false;
      float v0 = 0.f, v1 = 0.f;
      while (true) {
        if (!d0) {
          const unsigned long long x = __hip_atomic_load(&sb[i0],
              __ATOMIC_RELAXED, __HIP_MEMORY_SCOPE_AGENT);
          if ((unsigned)(x >> 32) == want) { v0 = __uint_as_float((unsigned)x); d0 = true; }
        }
        if (!d1) {
          const unsigned long long x = __hip_atomic_load(&sb[i1],
              __ATOMIC_RELAXED, __HIP_MEMORY_SCOPE_AGENT);
          if ((unsigned)(x >> 32) == want) { v1 = __uint_as_float((unsigned)x); d1 = true; }
        }
        if (d0 && d1) break;
        __builtin_amdgcn_s_sleep(1);
      }
      hb[i0] = v0; hb[i1] = v1;
    }
    __syncthreads();

    // ---- hx[u] = h_prev[u*64 + lane]  (conflict-free LDS b32 reads) ----
    float hx[16];
#pragma unroll
    for (int u = 0; u < 16; ++u) hx[u] = hb[u * 64 + lane];

    float d[6];
#pragma unroll
    for (int q = 0; q < 6; ++q) {
      float acc = 0.f;
#pragma unroll
      for (int u = 0; u < 16; ++u) acc += wv[q][u] * hx[u];
      d[q] = acc;
    }
#pragma unroll
    for (int q = 0; q < 6; ++q) d[q] = warp_sum(d[q]);

    if (lane == 0) {
      const float ho0 = hb[j], ho1 = hb[j + 1];  // exact h_prev from LDS
      const float r0 = sigmoidf_(gir.x + d[0] + bhr.x);
      const float r1 = sigmoidf_(gir.y + d[1] + bhr.y);
      const float z0 = sigmoidf_(giz.x + d[2] + bhz.x);
      const float z1 = sigmoidf_(giz.y + d[3] + bhz.y);
      const float n0 = tanhf_(gin.x + r0 * (d[4] + bhn.x));
      const float n1 = tanhf_(gin.y + r1 * (d[5] + bhn.y));
      float2 hn;
      hn.x = (1.f - z0) * n0 + z0 * ho0;
      hn.y = (1.f - z1) * n1 + z1 * ho1;
      *(float2*)(rnn + (size_t)t * kH + j) = hn;  // for downstream kernels
      const unsigned long long tagw = ((unsigned long long)(t + 1)) << 32;
      __hip_atomic_store(&step[(size_t)t * kH + j], tagw | __float_as_uint(hn.x),
                         __ATOMIC_RELAXED, __HIP_MEMORY_SCOPE_AGENT);
      __hip_atomic_store(&step[(size_t)t * kH + j + 1], tagw | __float_as_uint(hn.y),
                         __ATOMIC_RELAXED, __HIP_MEMORY_SCOPE_AGENT);
    }
    // no trailing barrier: next iteration stages into the OTHER hs buffer;
    // a wave cannot reach iteration t+2 (which would overwrite this one)
    // without every wave passing the t+1 barrier first.
  }
}

// ---------------- w2h[k] = sum_h v_attn[h] * W_attn[h][H+k] ----------------
// (softmax is shift-invariant: the h_bc half of cat and b_attn drop out)
__global__ __launch_bounds__(256) void k_w2h(const float* __restrict__ W_attn,
    const float* __restrict__ v_attn, float* __restrict__ w2h) {
  __shared__ float4 red[256];
  const int t  = threadIdx.x;
  const int k0 = kH + blockIdx.x * 4;  // absolute column in W_attn
  float ax = 0, ay = 0, az = 0, aw = 0;
  for (int h = t; h < kH; h += 256) {
    const float vh = v_attn[h];
    const float4 wq = *(const float4*)(W_attn + (size_t)h * 2048 + k0);
    ax += vh * wq.x; ay += vh * wq.y; az += vh * wq.z; aw += vh * wq.w;
  }
  red[t] = make_float4(ax, ay, az, aw);
  __syncthreads();
  for (int s = 128; s > 0; s >>= 1) {
    if (t < s) {
      const float4 a = red[t], b = red[t + s];
      red[t] = make_float4(a.x + b.x, a.y + b.y, a.z + b.z, a.w + b.w);
    }
    __syncthreads();
  }
  if (t == 0) *(float4*)(w2h + blockIdx.x * 4) = red[0];
}

// ---------------- scores[b][s] = enc[s][b][:] . w2h ----------------
__global__ __launch_bounds__(256) void k_scores(const float* __restrict__ enc,
    const float* __restrict__ w2h, float* __restrict__ sc) {
  const int lane = threadIdx.x & 63;
  const int wg = blockIdx.x * 4 + (threadIdx.x >> 6);  // 0..16383
  const int b = wg & 63, s = wg >> 6;
  const float4* ep = (const float4*)(enc + ((size_t)s * kB + b) * kH) + lane * 4;
  const float4* wp = (const float4*)w2h + lane * 4;
  float acc = 0.f;
#pragma unroll
  for (int c = 0; c < 4; ++c) {
    const float4 e = ep[c], wq = wp[c];
    acc += e.x * wq.x + e.y * wq.y + e.z * wq.z + e.w * wq.w;
  }
  acc = warp_sum(acc);
  if (lane == 0) sc[b * kS + s] = acc;
}

// ---------------- softmax over s (64 rows of 256) -> attn output ----------------
__global__ __launch_bounds__(256) void k_softmax(const float* __restrict__ sc,
                                                 float* __restrict__ attn) {
  __shared__ float sm[4], ss[4];
  const int b = blockIdx.x, t = threadIdx.x, lane = t & 63, w = t >> 6;
  const float x = sc[b * kS + t];
  float m = warp_max_all(x);
  if (lane == 0) sm[w] = m;
  __syncthreads();
  m = fmaxf(fmaxf(sm[0], sm[1]), fmaxf(sm[2], sm[3]));
  const float e = __expf(x - m);
  float s = warp_sum_all(e);
  if (lane == 0) ss[w] = s;
  __syncthreads();
  s = ss[0] + ss[1] + ss[2] + ss[3];
  attn[b * kS + t] = e / s;
}

// ---------------- context partials ----------------
__global__ __launch_bounds__(256) void k_context(const float* __restrict__ enc,
    const float* __restrict__ attn, float* __restrict__ part) {
  const int b  = blockIdx.x & 63;
  const int ch = blockIdx.x >> 6;
  const int h0 = threadIdx.x * 4;
  float ax = 0, ay = 0, az = 0, aw = 0;
  const int s0 = ch * 64;
#pragma unroll 4
  for (int s = s0; s < s0 + 64; ++s) {
    const float a = attn[b * kS + s];
    const float4 v = *(const float4*)(enc + ((size_t)s * kB + b) * kH + h0);
    ax += a * v.x; ay += a * v.y; az += a * v.z; aw += a * v.w;
  }
  *(float4*)(part + ((size_t)ch * kB + b) * kH + h0) =
      make_float4(ax, ay, az, aw);
}

// ---------------- context sum + hidden output copy ----------------
__global__ __launch_bounds__(256) void k_ctxsum(const float* __restrict__ part,
    const float* __restrict__ rnn, float* __restrict__ ctx,
    float* __restrict__ hid) {
  const int b = blockIdx.x;
  const int h0 = threadIdx.x * 4;
  float4 s = *(const float4*)(part + ((size_t)0 * kB + b) * kH + h0);
#pragma unroll
  for (int c = 1; c < 4; ++c) {
    const float4 p = *(const float4*)(part + ((size_t)c * kB + b) * kH + h0);
    s.x += p.x; s.y += p.y; s.z += p.z; s.w += p.w;
  }
  *(float4*)(ctx + (size_t)b * kH + h0) = s;
  if (b < 4) {
    const int i = b * 256 + threadIdx.x;
    hid[i] = rnn[63 * kH + i];
  }
}

// ---------------- coT[i][b] = tanh([rnn,ctx][b] . W_concat[i] + b_c[i]) ----------------
__global__ __launch_bounds__(256) void k_concat(const float* __restrict__ rnn,
    const float* __restrict__ ctx, const float* __restrict__ W_c,
    const float* __restrict__ b_c, float* __restrict__ coT) {
  const int lane = threadIdx.x & 63;
  const int i = blockIdx.x * 4 + (threadIdx.x >> 6);  // 0..1023
  float wreg[32];
  {
    const float4* wp = (const float4*)(W_c + (size_t)i * 2048) + lane * 8;
#pragma unroll
    for (int c = 0; c < 8; ++c) {
      const float4 f = wp[c];
      wreg[c * 4 + 0] = f.x; wreg[c * 4 + 1] = f.y;
      wreg[c * 4 + 2] = f.z; wreg[c * 4 + 3] = f.w;
    }
  }
  const float bc = b_c[i];
  const int jcol = lane * 32;
  const float* xbase = (jcol < kH) ? (rnn + jcol) : (ctx + (jcol - kH));
  for (int b = 0; b < kB; ++b) {
    const float* xr = xbase + (size_t)b * kH;
    float acc = 0.f;
#pragma unroll
    for (int c = 0; c < 8; ++c) {
      const float4 x = *(const float4*)(xr + c * 4);
      acc += wreg[c * 4 + 0] * x.x + wreg[c * 4 + 1] * x.y +
             wreg[c * 4 + 2] * x.z + wreg[c * 4 + 3] * x.w;
    }
    acc = warp_sum(acc);
    if (lane == 0) coT[(size_t)i * kB + b] = tanhf(acc + bc);
  }
}

// ---------------- out[b][v] = coT[:,b] . W_out[v] + b_out[v] ----------------
// R2 rewrite. Old version: 1000 wave-units (1 wave/SIMD, no TLP) issuing
// wave-UNIFORM float4 loads of W_out -> ~160 KB in flight device-wide ->
// W_out's 40 MB streamed at ~0.4 TB/s (~95 us). New version: 625 blocks of
// 256 threads; each block stages 16 W_out rows (64 KB) into LDS via 16
// outstanding coalesced float4 loads per thread (saturates HBM), then
// lane=b computes 4 v-rows per wave with broadcast LDS reads of W and
// coalesced coT loads. Floor: max(40MB @ ~6TB/s ~ 7us, 655M FMA ~ 8us).
__global__ __launch_bounds__(256) void k_out(const float* __restrict__ coT,
    const float* __restrict__ W_out, const float* __restrict__ b_out,
    float* __restrict__ out) {
  __shared__ float wlds[16 * kH];  // 64 KB: 16 rows of W_out
  const int v0 = blockIdx.x * 16;
  // ---- stage 16 rows, 16 loads in flight per thread ----
  {
    const float4* src = (const float4*)(W_out + (size_t)v0 * kH);
    float4 tmp[16];
#pragma unroll
    for (int c = 0; c < 16; ++c) tmp[c] = src[threadIdx.x + 256 * c];
    float4* dst = (float4*)wlds;
#pragma unroll
    for (int c = 0; c < 16; ++c) dst[threadIdx.x + 256 * c] = tmp[c];
  }
  __syncthreads();

  const int lane = threadIdx.x & 63;   // = b
  const int w    = threadIdx.x >> 6;   // wave: v-rows 4w..4w+3
  float acc[4] = {0.f, 0.f, 0.f, 0.f};
#pragma unroll 2
  for (int h = 0; h < kH; h += 4) {
    const float x0 = coT[(size_t)(h + 0) * kB + lane];
    const float x1 = coT[(size_t)(h + 1) * kB + lane];
    const float x2 = coT[(size_t)(h + 2) * kB + lane];
    const float x3 = coT[(size_t)(h + 3) * kB + lane];
#pragma unroll
    for (int vi = 0; vi < 4; ++vi) {
      const float4 wq = *(const float4*)&wlds[(w * 4 + vi) * kH + h];
      acc[vi] += wq.x * x0 + wq.y * x1 + wq.z * x2 + wq.w * x3;
    }
  }
  const float4 bq = *(const float4*)(b_out + v0 + w * 4);
  float4 r;
  r.x = acc[0] + bq.x; r.y = acc[1] + bq.y;
  r.z = acc[2] + bq.z; r.w = acc[3] + bq.w;
  *(float4*)&out[(size_t)lane * kV + v0 + w * 4] = r;
}

// ---------------- launcher ----------------
extern "C" void kernel_launch(void* const* d_in, const int* in_sizes, int n_in,
                              void* d_out, int out_size, void* d_ws,
                              size_t ws_size, hipStream_t stream) {
  const int*   seq    = (const int*)  d_in[0];
  const float* h0     = (const float*)d_in[1];
  const float* enc    = (const float*)d_in[2];
  const float* emb    = (const float*)d_in[3];
  const float* W_ih   = (const float*)d_in[4];
  const float* W_hh   = (const float*)d_in[5];
  const float* b_ih   = (const float*)d_in[6];
  const float* b_hh   = (const float*)d_in[7];
  const float* W_attn = (const float*)d_in[8];
  // d_in[9] = b_attn: drops out of softmax (shift invariance)
  const float* v_attn = (const float*)d_in[10];
  const float* W_conc = (const float*)d_in[11];
  const float* b_conc = (const float*)d_in[12];
  const float* W_outp = (const float*)d_in[13];
  const float* b_outp = (const float*)d_in[14];

  float* out      = (float*)d_out;           // (B,V) = 640000
  float* out_hid  = out + 640000;            // (1,1,H) = 1024
  float* out_attn = out + 641024;            // (B,1,S) = 16384

  float* ws = (float*)d_ws;
  float* GI   = ws;                      // 64*3072   = 196608
  float* RNN  = ws + 196608;             // 64*1024   =  65536
  unsigned long long* STEP =
      (unsigned long long*)(ws + 262144);  // 64*1024 u64 = 131072 floats
  float* W2H  = ws + 393216;             // 1024
  float* SC   = ws + 394240;             // 64*256    =  16384
  float* PART = ws + 410624;             // 4*64*1024 = 262144
  float* CTX  = ws + 672768;             // 64*1024   =  65536
  float* COT  = ws + 738304;             // 1024*64   =  65536 (end 803840 floats)

  k_gi<<<768, 256, 0, stream>>>(seq, emb, W_ih, b_ih, GI);
  k_gru<<<64, 512, 0, stream>>>(h0, W_hh, b_hh, GI, RNN, STEP);
  k_w2h<<<256, 256, 0, stream>>>(W_attn, v_attn, W2H);
  k_scores<<<4096, 256, 0, stream>>>(enc, W2H, SC);
  k_softmax<<<64, 256, 0, stream>>>(SC, out_attn);
  k_context<<<256, 256, 0, stream>>>(enc, out_attn, PART);
  k_ctxsum<<<64, 256, 0, stream>>>(PART, RNN, CTX, out_hid);
  k_concat<<<256, 256, 0, stream>>>(RNN, CTX, W_conc, b_conc, COT);
  k_out<<<625, 256, 0, stream>>>(COT, W_outp, b_outp, out);
}

// Round 3
// 610.041 us; speedup vs baseline: 1.0463x; 1.0463x over previous
//
#include <hip/hip_runtime.h>
#include <math.h>

// Problem constants
#define kH  1024
#define kB  64
#define kS  256
#define kV  10000
#define kH3 3072

// ---------------- helpers ----------------
__device__ __forceinline__ float warp_sum(float v) {
#pragma unroll
  for (int off = 32; off > 0; off >>= 1) v += __shfl_down(v, off, 64);
  return v;  // valid on lane 0
}
__device__ __forceinline__ float warp_max_all(float v) {
#pragma unroll
  for (int off = 32; off > 0; off >>= 1) v = fmaxf(v, __shfl_xor(v, off, 64));
  return v;
}
__device__ __forceinline__ float warp_sum_all(float v) {
#pragma unroll
  for (int off = 32; off > 0; off >>= 1) v += __shfl_xor(v, off, 64);
  return v;
}
__device__ __forceinline__ float sigmoidf_(float x) {
  return __fdividef(1.0f, 1.0f + __expf(-x));
}
// fast tanh via exp(-2|x|): no overflow, ~8 instrs instead of libm call.
__device__ __forceinline__ float tanhf_(float x) {
  const float t = __expf(-2.0f * fabsf(x));
  const float r = __fdividef(1.0f - t, 1.0f + t);
  return copysignf(r, x);
}

// ---------------- GI = emb[seq] @ W_ih^T + b_ih  (64 x 3072) ----------------
// grid 768 x 256: one wave per output row r (3072 rows), loop over t=0..63.
__global__ __launch_bounds__(256) void k_gi(const int* __restrict__ seq,
    const float* __restrict__ emb, const float* __restrict__ W_ih,
    const float* __restrict__ b_ih, float* __restrict__ GI) {
  const int lane = threadIdx.x & 63;
  const int r = blockIdx.x * 4 + (threadIdx.x >> 6);
  const float4* wp = (const float4*)(W_ih + (size_t)r * kH) + lane * 4;
  const float4 w0 = wp[0], w1 = wp[1], w2 = wp[2], w3 = wp[3];
  const float br = b_ih[r];
  for (int t = 0; t < kB; ++t) {
    const int tok = seq[t];
    const float4* xp = (const float4*)(emb + (size_t)tok * kH) + lane * 4;
    const float4 x0 = xp[0], x1 = xp[1], x2 = xp[2], x3 = xp[3];
    float acc = w0.x*x0.x + w0.y*x0.y + w0.z*x0.z + w0.w*x0.w;
    acc += w1.x*x1.x + w1.y*x1.y + w1.z*x1.z + w1.w*x1.w;
    acc += w2.x*x2.x + w2.y*x2.y + w2.z*x2.z + w2.w*x2.w;
    acc += w3.x*x3.x + w3.y*x3.y + w3.z*x3.z + w3.w*x3.w;
    acc = warp_sum(acc);
    if (lane == 0) GI[(size_t)t * kH3 + r] = acc + br;
  }
}

// ---------------- Persistent GRU scan (64 sequential steps) ----------------
// R3 structure: 64 blocks x 1024 threads (16 waves/CU, one block per CU).
// Wave w (0..15) of block bid owns ONE output element j = 16*bid + w.
// Per-thread weights: wv[3][16] = 48 floats (r,z,n rows of W_hh, lane-sliced)
// -> fits comfortably under the 128-VGPR budget at 4 waves/SIMD, so the asm
// pins now guarantee true residency (R1: 96/thread -> compiler re-loaded from
// L2 every step; R2: pin forced them -> scratch spill; both on the serial
// critical path).
//
// Handshake unchanged: relaxed agent-scope u64 atomics carrying
// (tag = t+1 | float bits); single-location atomicity -> no fences. Each
// thread now polls exactly ONE slot. ws poison 0xAAAAAAAA never matches tags.
__global__ __launch_bounds__(1024, 4) void k_gru(const float* __restrict__ h0,
    const float* __restrict__ W_hh, const float* __restrict__ b_hh,
    const float* __restrict__ GI, float* __restrict__ rnn,
    unsigned long long* __restrict__ step) {
  __shared__ float hs[2][kH];
  const int tid  = threadIdx.x;        // 0..1023
  const int lane = tid & 63;
  const int w    = tid >> 6;           // 0..15
  const int bid  = blockIdx.x;         // 0..63
  const int j    = bid * 16 + w;       // output element owned by this wave

  // wv[q][u] = W_hh[q*kH + j][u*64 + lane]  (coalesced load per (q,u))
  float wv[3][16];
#pragma unroll
  for (int q = 0; q < 3; ++q) {
    const float* base = W_hh + ((size_t)q * kH + j) * kH + lane;
#pragma unroll
    for (int u = 0; u < 16; ++u) wv[q][u] = base[u * 64];
  }
  // Pin: opaque asm result -> no rematerialization; 48 regs fits the budget.
#pragma unroll
  for (int q = 0; q < 3; ++q)
#pragma unroll
    for (int u = 0; u < 16; ++u)
      asm volatile("" : "+v"(wv[q][u]));

  const float bhr = b_hh[j];
  const float bhz = b_hh[kH + j];
  const float bhn = b_hh[2 * kH + j];

  for (int t = 0; t < kB; ++t) {
    // ---- prefetch GI[t] (h-independent): latency hides under the poll ----
    float gir = GI[(size_t)t * kH3 + j];
    float giz = GI[(size_t)t * kH3 + kH + j];
    float gin = GI[(size_t)t * kH3 + 2 * kH + j];
    asm volatile("" :: "v"(gir), "v"(giz), "v"(gin));

    float* hb = hs[t & 1];
    // ---- stage h_prev into LDS (1 slot per thread) ----
    if (t == 0) {
      hb[tid] = h0[tid];
    } else {
      const unsigned long long* sb = step + (size_t)(t - 1) * kH;
      const unsigned want = (unsigned)t;  // producer of step t-1 wrote tag t
      float v0;
      while (true) {
        const unsigned long long x = __hip_atomic_load(&sb[tid],
            __ATOMIC_RELAXED, __HIP_MEMORY_SCOPE_AGENT);
        if ((unsigned)(x >> 32) == want) { v0 = __uint_as_float((unsigned)x); break; }
        __builtin_amdgcn_s_sleep(1);
      }
      hb[tid] = v0;
    }
    __syncthreads();

    // ---- hx[u] = h_prev[u*64 + lane]  (2-way LDS aliasing = free) ----
    float hx[16];
#pragma unroll
    for (int u = 0; u < 16; ++u) hx[u] = hb[u * 64 + lane];

    float d[3];
#pragma unroll
    for (int q = 0; q < 3; ++q) {
      float acc = 0.f;
#pragma unroll
      for (int u = 0; u < 16; ++u) acc += wv[q][u] * hx[u];
      d[q] = acc;
    }
#pragma unroll
    for (int q = 0; q < 3; ++q) d[q] = warp_sum(d[q]);

    if (lane == 0) {
      const float ho = hb[j];  // exact h_prev from LDS
      const float r = sigmoidf_(gir + d[0] + bhr);
      const float z = sigmoidf_(giz + d[1] + bhz);
      const float n = tanhf_(gin + r * (d[2] + bhn));
      const float hn = (1.f - z) * n + z * ho;
      rnn[(size_t)t * kH + j] = hn;  // for downstream kernels
      __hip_atomic_store(&step[(size_t)t * kH + j],
                         (((unsigned long long)(t + 1)) << 32) | __float_as_uint(hn),
                         __ATOMIC_RELAXED, __HIP_MEMORY_SCOPE_AGENT);
    }
    // no trailing barrier: next iteration stages into the OTHER hs buffer;
    // a wave cannot reach iteration t+2 (overwriting this buffer) without
    // every wave passing the t+1 barrier, which follows their reads here.
  }
}

// ---------------- w2h[k] = sum_h v_attn[h] * W_attn[h][H+k] ----------------
// (softmax is shift-invariant: the h_bc half of cat and b_attn drop out)
__global__ __launch_bounds__(256) void k_w2h(const float* __restrict__ W_attn,
    const float* __restrict__ v_attn, float* __restrict__ w2h) {
  __shared__ float4 red[256];
  const int t  = threadIdx.x;
  const int k0 = kH + blockIdx.x * 4;  // absolute column in W_attn
  float ax = 0, ay = 0, az = 0, aw = 0;
  for (int h = t; h < kH; h += 256) {
    const float vh = v_attn[h];
    const float4 wq = *(const float4*)(W_attn + (size_t)h * 2048 + k0);
    ax += vh * wq.x; ay += vh * wq.y; az += vh * wq.z; aw += vh * wq.w;
  }
  red[t] = make_float4(ax, ay, az, aw);
  __syncthreads();
  for (int s = 128; s > 0; s >>= 1) {
    if (t < s) {
      const float4 a = red[t], b = red[t + s];
      red[t] = make_float4(a.x + b.x, a.y + b.y, a.z + b.z, a.w + b.w);
    }
    __syncthreads();
  }
  if (t == 0) *(float4*)(w2h + blockIdx.x * 4) = red[0];
}

// ---------------- scores[b][s] = enc[s][b][:] . w2h ----------------
__global__ __launch_bounds__(256) void k_scores(const float* __restrict__ enc,
    const float* __restrict__ w2h, float* __restrict__ sc) {
  const int lane = threadIdx.x & 63;
  const int wg = blockIdx.x * 4 + (threadIdx.x >> 6);  // 0..16383
  const int b = wg & 63, s = wg >> 6;
  const float4* ep = (const float4*)(enc + ((size_t)s * kB + b) * kH) + lane * 4;
  const float4* wp = (const float4*)w2h + lane * 4;
  float acc = 0.f;
#pragma unroll
  for (int c = 0; c < 4; ++c) {
    const float4 e = ep[c], wq = wp[c];
    acc += e.x * wq.x + e.y * wq.y + e.z * wq.z + e.w * wq.w;
  }
  acc = warp_sum(acc);
  if (lane == 0) sc[b * kS + s] = acc;
}

// ---------------- softmax over s (64 rows of 256) -> attn output ----------------
__global__ __launch_bounds__(256) void k_softmax(const float* __restrict__ sc,
                                                 float* __restrict__ attn) {
  __shared__ float sm[4], ss[4];
  const int b = blockIdx.x, t = threadIdx.x, lane = t & 63, w = t >> 6;
  const float x = sc[b * kS + t];
  float m = warp_max_all(x);
  if (lane == 0) sm[w] = m;
  __syncthreads();
  m = fmaxf(fmaxf(sm[0], sm[1]), fmaxf(sm[2], sm[3]));
  const float e = __expf(x - m);
  float s = warp_sum_all(e);
  if (lane == 0) ss[w] = s;
  __syncthreads();
  s = ss[0] + ss[1] + ss[2] + ss[3];
  attn[b * kS + t] = e / s;
}

// ---------------- context partials ----------------
__global__ __launch_bounds__(256) void k_context(const float* __restrict__ enc,
    const float* __restrict__ attn, float* __restrict__ part) {
  const int b  = blockIdx.x & 63;
  const int ch = blockIdx.x >> 6;
  const int h0 = threadIdx.x * 4;
  float ax = 0, ay = 0, az = 0, aw = 0;
  const int s0 = ch * 64;
#pragma unroll 4
  for (int s = s0; s < s0 + 64; ++s) {
    const float a = attn[b * kS + s];
    const float4 v = *(const float4*)(enc + ((size_t)s * kB + b) * kH + h0);
    ax += a * v.x; ay += a * v.y; az += a * v.z; aw += a * v.w;
  }
  *(float4*)(part + ((size_t)ch * kB + b) * kH + h0) =
      make_float4(ax, ay, az, aw);
}

// ---------------- context sum + hidden output copy ----------------
__global__ __launch_bounds__(256) void k_ctxsum(const float* __restrict__ part,
    const float* __restrict__ rnn, float* __restrict__ ctx,
    float* __restrict__ hid) {
  const int b = blockIdx.x;
  const int h0 = threadIdx.x * 4;
  float4 s = *(const float4*)(part + ((size_t)0 * kB + b) * kH + h0);
#pragma unroll
  for (int c = 1; c < 4; ++c) {
    const float4 p = *(const float4*)(part + ((size_t)c * kB + b) * kH + h0);
    s.x += p.x; s.y += p.y; s.z += p.z; s.w += p.w;
  }
  *(float4*)(ctx + (size_t)b * kH + h0) = s;
  if (b < 4) {
    const int i = b * 256 + threadIdx.x;
    hid[i] = rnn[63 * kH + i];
  }
}

// ---------------- coT[i][b] = tanh([rnn,ctx][b] . W_concat[i] + b_c[i]) ----------------
// R3: split the b-loop 4 ways (grid 256 -> 1024 blocks) for 4x TLP. R2 had
// 1 wave/SIMD with L2-latency-bound lane-scattered x loads and nothing to
// hide the latency. W_c rows are re-read 4x (L2-resident, cheap).
__global__ __launch_bounds__(256) void k_concat(const float* __restrict__ rnn,
    const float* __restrict__ ctx, const float* __restrict__ W_c,
    const float* __restrict__ b_c, float* __restrict__ coT) {
  const int lane = threadIdx.x & 63;
  const int iq = blockIdx.x >> 2;                 // 0..255
  const int bq = blockIdx.x & 3;                  // 0..3
  const int i  = iq * 4 + (threadIdx.x >> 6);     // 0..1023
  float wreg[32];
  {
    const float4* wp = (const float4*)(W_c + (size_t)i * 2048) + lane * 8;
#pragma unroll
    for (int c = 0; c < 8; ++c) {
      const float4 f = wp[c];
      wreg[c * 4 + 0] = f.x; wreg[c * 4 + 1] = f.y;
      wreg[c * 4 + 2] = f.z; wreg[c * 4 + 3] = f.w;
    }
  }
  const float bc = b_c[i];
  const int jcol = lane * 32;
  const float* xbase = (jcol < kH) ? (rnn + jcol) : (ctx + (jcol - kH));
  for (int b = bq * 16; b < bq * 16 + 16; ++b) {
    const float* xr = xbase + (size_t)b * kH;
    float acc = 0.f;
#pragma unroll
    for (int c = 0; c < 8; ++c) {
      const float4 x = *(const float4*)(xr + c * 4);
      acc += wreg[c * 4 + 0] * x.x + wreg[c * 4 + 1] * x.y +
             wreg[c * 4 + 2] * x.z + wreg[c * 4 + 3] * x.w;
    }
    acc = warp_sum(acc);
    if (lane == 0) coT[(size_t)i * kB + b] = tanhf(acc + bc);
  }
}

// ---------------- out[b][v] = coT[:,b] . W_out[v] + b_out[v] ----------------
// 625 blocks x 256 threads; stage 16 W_out rows (64 KB) in LDS with 16
// outstanding coalesced float4 loads/thread; lane=b; broadcast LDS W reads.
__global__ __launch_bounds__(256) void k_out(const float* __restrict__ coT,
    const float* __restrict__ W_out, const float* __restrict__ b_out,
    float* __restrict__ out) {
  __shared__ float wlds[16 * kH];  // 64 KB: 16 rows of W_out
  const int v0 = blockIdx.x * 16;
  {
    const float4* src = (const float4*)(W_out + (size_t)v0 * kH);
    float4 tmp[16];
#pragma unroll
    for (int c = 0; c < 16; ++c) tmp[c] = src[threadIdx.x + 256 * c];
    float4* dst = (float4*)wlds;
#pragma unroll
    for (int c = 0; c < 16; ++c) dst[threadIdx.x + 256 * c] = tmp[c];
  }
  __syncthreads();

  const int lane = threadIdx.x & 63;   // = b
  const int w    = threadIdx.x >> 6;   // wave: v-rows 4w..4w+3
  float acc[4] = {0.f, 0.f, 0.f, 0.f};
#pragma unroll 2
  for (int h = 0; h < kH; h += 4) {
    const float x0 = coT[(size_t)(h + 0) * kB + lane];
    const float x1 = coT[(size_t)(h + 1) * kB + lane];
    const float x2 = coT[(size_t)(h + 2) * kB + lane];
    const float x3 = coT[(size_t)(h + 3) * kB + lane];
#pragma unroll
    for (int vi = 0; vi < 4; ++vi) {
      const float4 wq = *(const float4*)&wlds[(w * 4 + vi) * kH + h];
      acc[vi] += wq.x * x0 + wq.y * x1 + wq.z * x2 + wq.w * x3;
    }
  }
  const float4 bq = *(const float4*)(b_out + v0 + w * 4);
  float4 r;
  r.x = acc[0] + bq.x; r.y = acc[1] + bq.y;
  r.z = acc[2] + bq.z; r.w = acc[3] + bq.w;
  *(float4*)&out[(size_t)lane * kV + v0 + w * 4] = r;
}

// ---------------- launcher ----------------
extern "C" void kernel_launch(void* const* d_in, const int* in_sizes, int n_in,
                              void* d_out, int out_size, void* d_ws,
                              size_t ws_size, hipStream_t stream) {
  const int*   seq    = (const int*)  d_in[0];
  const float* h0     = (const float*)d_in[1];
  const float* enc    = (const float*)d_in[2];
  const float* emb    = (const float*)d_in[3];
  const float* W_ih   = (const float*)d_in[4];
  const float* W_hh   = (const float*)d_in[5];
  const float* b_ih   = (const float*)d_in[6];
  const float* b_hh   = (const float*)d_in[7];
  const float* W_attn = (const float*)d_in[8];
  // d_in[9] = b_attn: drops out of softmax (shift invariance)
  const float* v_attn = (const float*)d_in[10];
  const float* W_conc = (const float*)d_in[11];
  const float* b_conc = (const float*)d_in[12];
  const float* W_outp = (const float*)d_in[13];
  const float* b_outp = (const float*)d_in[14];

  float* out      = (float*)d_out;           // (B,V) = 640000
  float* out_hid  = out + 640000;            // (1,1,H) = 1024
  float* out_attn = out + 641024;            // (B,1,S) = 16384

  float* ws = (float*)d_ws;
  float* GI   = ws;                      // 64*3072   = 196608
  float* RNN  = ws + 196608;             // 64*1024   =  65536
  unsigned long long* STEP =
      (unsigned long long*)(ws + 262144);  // 64*1024 u64 = 131072 floats
  float* W2H  = ws + 393216;             // 1024
  float* SC   = ws + 394240;             // 64*256    =  16384
  float* PART = ws + 410624;             // 4*64*1024 = 262144
  float* CTX  = ws + 672768;             // 64*1024   =  65536
  float* COT  = ws + 738304;             // 1024*64   =  65536 (end 803840 floats)

  k_gi<<<768, 256, 0, stream>>>(seq, emb, W_ih, b_ih, GI);
  k_gru<<<64, 1024, 0, stream>>>(h0, W_hh, b_hh, GI, RNN, STEP);
  k_w2h<<<256, 256, 0, stream>>>(W_attn, v_attn, W2H);
  k_scores<<<4096, 256, 0, stream>>>(enc, W2H, SC);
  k_softmax<<<64, 256, 0, stream>>>(SC, out_attn);
  k_context<<<256, 256, 0, stream>>>(enc, out_attn, PART);
  k_ctxsum<<<64, 256, 0, stream>>>(PART, RNN, CTX, out_hid);
  k_concat<<<1024, 256, 0, stream>>>(RNN, CTX, W_conc, b_conc, COT);
  k_out<<<625, 256, 0, stream>>>(COT, W_outp, b_outp, out);
}

// Round 5
// 539.198 us; speedup vs baseline: 1.1837x; 1.1314x over previous
//
#include <hip/hip_runtime.h>
#include <math.h>

// Problem constants
#define kH  1024
#define kB  64
#define kS  256
#define kV  10000
#define kH3 3072

// ---------------- helpers ----------------
__device__ __forceinline__ float warp_sum(float v) {
#pragma unroll
  for (int off = 32; off > 0; off >>= 1) v += __shfl_down(v, off, 64);
  return v;  // valid on lane 0
}
__device__ __forceinline__ float warp_max_all(float v) {
#pragma unroll
  for (int off = 32; off > 0; off >>= 1) v = fmaxf(v, __shfl_xor(v, off, 64));
  return v;
}
__device__ __forceinline__ float warp_sum_all(float v) {
#pragma unroll
  for (int off = 32; off > 0; off >>= 1) v += __shfl_xor(v, off, 64);
  return v;
}
__device__ __forceinline__ float sigmoidf_(float x) {
  return __fdividef(1.0f, 1.0f + __expf(-x));
}
// fast tanh via exp(-2|x|): no overflow, ~8 instrs instead of libm call.
__device__ __forceinline__ float tanhf_(float x) {
  const float t = __expf(-2.0f * fabsf(x));
  const float r = __fdividef(1.0f - t, 1.0f + t);
  return copysignf(r, x);
}

// ---------------- GI = emb[seq] @ W_ih^T + b_ih  (64 x 3072) ----------------
// grid 768 x 256: one wave per output row r (3072 rows), loop over t=0..63.
__global__ __launch_bounds__(256) void k_gi(const int* __restrict__ seq,
    const float* __restrict__ emb, const float* __restrict__ W_ih,
    const float* __restrict__ b_ih, float* __restrict__ GI) {
  const int lane = threadIdx.x & 63;
  const int r = blockIdx.x * 4 + (threadIdx.x >> 6);
  const float4* wp = (const float4*)(W_ih + (size_t)r * kH) + lane * 4;
  const float4 w0 = wp[0], w1 = wp[1], w2 = wp[2], w3 = wp[3];
  const float br = b_ih[r];
  for (int t = 0; t < kB; ++t) {
    const int tok = seq[t];
    const float4* xp = (const float4*)(emb + (size_t)tok * kH) + lane * 4;
    const float4 x0 = xp[0], x1 = xp[1], x2 = xp[2], x3 = xp[3];
    float acc = w0.x*x0.x + w0.y*x0.y + w0.z*x0.z + w0.w*x0.w;
    acc += w1.x*x1.x + w1.y*x1.y + w1.z*x1.z + w1.w*x1.w;
    acc += w2.x*x2.x + w2.y*x2.y + w2.z*x2.z + w2.w*x2.w;
    acc += w3.x*x3.x + w3.y*x3.y + w3.z*x3.z + w3.w*x3.w;
    acc = warp_sum(acc);
    if (lane == 0) GI[(size_t)t * kH3 + r] = acc + br;
  }
}

// ---------------- Persistent GRU scan (64 sequential steps) ----------------
// R4 structure (resubmitted R5: R4 bench died at container level, no
// counters; re-audit found no deadlock/OOB — see capacity check below).
// 256 blocks x 256 threads (one block per CU). Block bid owns
// h[4*bid .. 4*bid+3]; wave w (0..3) owns element j = 4*bid + w.
//
// Co-residency capacity: 56 KB LDS/block, 4 waves/block -> per-CU capacity
// min(floor(160/56)=2, 32/4=8) >= 1; 256 blocks on 256 CUs always fully
// resident; spin-wait cannot deadlock.
//
// KEY CHANGE vs R3: W_hh rows live in LDS (48 KB/block), not registers.
// Three rounds of evidence (VGPR=76/76/44) proved regalloc will NOT keep a
// per-thread weight panel resident across the t-loop — it re-loads from
// L2 (R1) or scratch (R2/R3) on the serial critical path every step.
// LDS is architecturally resident: 12 ds_read_b128/lane/step at ~12cy
// throughput, overlapped with FMAs (~0.3 us), replacing ~1-2 us of
// global/scratch reloads.
//
// Handshake unchanged: relaxed agent-scope u64 atomics carrying
// (tag = t+1 | float bits); single-location atomicity -> no fences.
// Each thread polls 4 slots (independent loads -> one RTT, pipelined).
// ws poison 0xAAAAAAAA never matches tags 1..64.
__global__ __launch_bounds__(256) void k_gru(const float* __restrict__ h0,
    const float* __restrict__ W_hh, const float* __restrict__ b_hh,
    const float* __restrict__ GI, float* __restrict__ rnn,
    unsigned long long* __restrict__ step) {
  __shared__ float4 wlds4[12 * 256];      // 48 KB: 12 rows (3 gates x 4 elems)
  __shared__ __align__(16) float hs[2][kH];  // 8 KB double buffer
  const int tid  = threadIdx.x;           // 0..255
  const int lane = tid & 63;
  const int w    = tid >> 6;              // 0..3
  const int bid  = blockIdx.x;            // 0..255
  const int j    = bid * 4 + w;           // output element owned by this wave

  // ---- stage 12 W_hh rows into LDS (coalesced float4, conflict-free) ----
  // row = q*4 + r  maps to global row  q*kH + bid*4 + r   (q = gate 0..2)
#pragma unroll
  for (int c = 0; c < 12; ++c) {
    const int f    = c * 256 + tid;       // 0..3071
    const int row  = f >> 8;              // 0..11
    const int col4 = f & 255;             // 0..255
    const int q    = row >> 2, r = row & 3;
    wlds4[f] = ((const float4*)(W_hh + ((size_t)q * kH + bid * 4 + r) * kH))[col4];
  }

  const float bhr = b_hh[j];
  const float bhz = b_hh[kH + j];
  const float bhn = b_hh[2 * kH + j];

  for (int t = 0; t < kB; ++t) {
    // ---- prefetch GI[t] (h-independent): latency hides under the poll ----
    float gir = GI[(size_t)t * kH3 + j];
    float giz = GI[(size_t)t * kH3 + kH + j];
    float gin = GI[(size_t)t * kH3 + 2 * kH + j];
    asm volatile("" :: "v"(gir), "v"(giz), "v"(gin));

    float* hb = hs[t & 1];
    // ---- stage h_prev into LDS (4 slots per thread) ----
    if (t == 0) {
      ((float4*)hb)[tid] = ((const float4*)h0)[tid];
    } else {
      const unsigned long long* sb = step + (size_t)(t - 1) * kH;
      const unsigned want = (unsigned)t;  // producer of step t-1 wrote tag t
      const int i0 = tid * 4;
      bool done[4] = {false, false, false, false};
      float v[4];
      while (true) {
        bool all = true;
#pragma unroll
        for (int k = 0; k < 4; ++k) {
          if (!done[k]) {
            const unsigned long long x = __hip_atomic_load(&sb[i0 + k],
                __ATOMIC_RELAXED, __HIP_MEMORY_SCOPE_AGENT);
            if ((unsigned)(x >> 32) == want) {
              v[k] = __uint_as_float((unsigned)x);
              done[k] = true;
            } else {
              all = false;
            }
          }
        }
        if (all) break;
        __builtin_amdgcn_s_sleep(1);
      }
#pragma unroll
      for (int k = 0; k < 4; ++k) hb[i0 + k] = v[k];
    }
    __syncthreads();  // also orders the one-time weight ds_writes at t==0

    // ---- hx4[c] = h_prev float4 slice (conflict-free b128 reads) ----
    float4 hx4[4];
#pragma unroll
    for (int c = 0; c < 4; ++c) hx4[c] = ((const float4*)hb)[lane + 64 * c];

    // ---- d[q] = W_hh[q*kH+j][:] . h_prev  (weights from LDS) ----
    float d[3];
#pragma unroll
    for (int q = 0; q < 3; ++q) {
      float acc = 0.f;
#pragma unroll
      for (int c = 0; c < 4; ++c) {
        const float4 wq = wlds4[(q * 4 + w) * 256 + lane + 64 * c];
        const float4 h4 = hx4[c];
        acc += wq.x * h4.x + wq.y * h4.y + wq.z * h4.z + wq.w * h4.w;
      }
      d[q] = acc;
    }
#pragma unroll
    for (int q = 0; q < 3; ++q) d[q] = warp_sum(d[q]);

    if (lane == 0) {
      const float ho = hb[j];  // exact h_prev from LDS
      const float r = sigmoidf_(gir + d[0] + bhr);
      const float z = sigmoidf_(giz + d[1] + bhz);
      const float n = tanhf_(gin + r * (d[2] + bhn));
      const float hn = (1.f - z) * n + z * ho;
      rnn[(size_t)t * kH + j] = hn;  // for downstream kernels
      __hip_atomic_store(&step[(size_t)t * kH + j],
                         (((unsigned long long)(t + 1)) << 32) | __float_as_uint(hn),
                         __ATOMIC_RELAXED, __HIP_MEMORY_SCOPE_AGENT);
    }
    // no trailing barrier: next iteration stages into the OTHER hs buffer;
    // a wave cannot reach iteration t+2 (overwriting this buffer) without
    // every wave passing the t+1 barrier, which follows their reads here.
  }
}

// ---------------- w2h[k] = sum_h v_attn[h] * W_attn[h][H+k] ----------------
// (softmax is shift-invariant: the h_bc half of cat and b_attn drop out)
__global__ __launch_bounds__(256) void k_w2h(const float* __restrict__ W_attn,
    const float* __restrict__ v_attn, float* __restrict__ w2h) {
  __shared__ float4 red[256];
  const int t  = threadIdx.x;
  const int k0 = kH + blockIdx.x * 4;  // absolute column in W_attn
  float ax = 0, ay = 0, az = 0, aw = 0;
  for (int h = t; h < kH; h += 256) {
    const float vh = v_attn[h];
    const float4 wq = *(const float4*)(W_attn + (size_t)h * 2048 + k0);
    ax += vh * wq.x; ay += vh * wq.y; az += vh * wq.z; aw += vh * wq.w;
  }
  red[t] = make_float4(ax, ay, az, aw);
  __syncthreads();
  for (int s = 128; s > 0; s >>= 1) {
    if (t < s) {
      const float4 a = red[t], b = red[t + s];
      red[t] = make_float4(a.x + b.x, a.y + b.y, a.z + b.z, a.w + b.w);
    }
    __syncthreads();
  }
  if (t == 0) *(float4*)(w2h + blockIdx.x * 4) = red[0];
}

// ---------------- scores[b][s] = enc[s][b][:] . w2h ----------------
__global__ __launch_bounds__(256) void k_scores(const float* __restrict__ enc,
    const float* __restrict__ w2h, float* __restrict__ sc) {
  const int lane = threadIdx.x & 63;
  const int wg = blockIdx.x * 4 + (threadIdx.x >> 6);  // 0..16383
  const int b = wg & 63, s = wg >> 6;
  const float4* ep = (const float4*)(enc + ((size_t)s * kB + b) * kH) + lane * 4;
  const float4* wp = (const float4*)w2h + lane * 4;
  float acc = 0.f;
#pragma unroll
  for (int c = 0; c < 4; ++c) {
    const float4 e = ep[c], wq = wp[c];
    acc += e.x * wq.x + e.y * wq.y + e.z * wq.z + e.w * wq.w;
  }
  acc = warp_sum(acc);
  if (lane == 0) sc[b * kS + s] = acc;
}

// ---- fused softmax + context + ctxsum + hid copy (replaces 3 kernels) ----
// 64 blocks (one per b) x 1024 threads. Phase A: softmax over the 256
// scores (identical math/order to old k_softmax). Phase B: context
// accumulation, s-quarter per thread-group, 4-partial reduce in LDS
// (identical summation order to old k_context + k_ctxsum).
__global__ __launch_bounds__(1024) void k_ctx2(const float* __restrict__ sc,
    const float* __restrict__ enc, const float* __restrict__ rnn,
    float* __restrict__ attn, float* __restrict__ ctx,
    float* __restrict__ hid) {
  __shared__ float aw[kS];
  __shared__ float sm[4], ss[4];
  __shared__ float4 part4[1024];  // 16 KB
  const int b = blockIdx.x, tid = threadIdx.x;
  const int lane = tid & 63, w = tid >> 6;

  float x = 0.f, e = 0.f;
  if (tid < kS) {
    x = sc[b * kS + tid];
    const float m = warp_max_all(x);
    if (lane == 0) sm[w] = m;
  }
  __syncthreads();
  if (tid < kS) {
    const float m = fmaxf(fmaxf(sm[0], sm[1]), fmaxf(sm[2], sm[3]));
    e = __expf(x - m);
    const float s = warp_sum_all(e);
    if (lane == 0) ss[w] = s;
  }
  __syncthreads();
  if (tid < kS) {
    const float s = ss[0] + ss[1] + ss[2] + ss[3];
    const float a = e / s;
    attn[b * kS + tid] = a;   // output (B,1,S)
    aw[tid] = a;
  }
  if (b < 4 && tid < kS) {    // hidden output copy (independent)
    hid[b * kS + tid] = rnn[63 * kH + b * kS + tid];
  }
  __syncthreads();

  // Phase B: thread owns h-chunk hc (float4) within s-quarter sq.
  const int hc = tid & 255;
  const int sq = tid >> 8;    // 0..3
  const float4* encb = (const float4*)enc;
  float4 acc = make_float4(0.f, 0.f, 0.f, 0.f);
  const int s0 = sq * 64;
#pragma unroll 4
  for (int s = s0; s < s0 + 64; ++s) {
    const float a = aw[s];
    const float4 v = encb[((size_t)s * kB + b) * 256 + hc];
    acc.x += a * v.x; acc.y += a * v.y; acc.z += a * v.z; acc.w += a * v.w;
  }
  part4[tid] = acc;
  __syncthreads();
  if (tid < 256) {
    const float4 p0 = part4[tid], p1 = part4[tid + 256];
    const float4 p2 = part4[tid + 512], p3 = part4[tid + 768];
    float4 r;
    r.x = p0.x + p1.x + p2.x + p3.x;
    r.y = p0.y + p1.y + p2.y + p3.y;
    r.z = p0.z + p1.z + p2.z + p3.z;
    r.w = p0.w + p1.w + p2.w + p3.w;
    ((float4*)(ctx + (size_t)b * kH))[tid] = r;
  }
}

// ---------------- coT[i][b] = tanh([rnn,ctx][b] . W_concat[i] + b_c[i]) ----------------
// b-loop split 4 ways (1024 blocks) for TLP; W_c rows re-read 4x (L2).
__global__ __launch_bounds__(256) void k_concat(const float* __restrict__ rnn,
    const float* __restrict__ ctx, const float* __restrict__ W_c,
    const float* __restrict__ b_c, float* __restrict__ coT) {
  const int lane = threadIdx.x & 63;
  const int iq = blockIdx.x >> 2;                 // 0..255
  const int bq = blockIdx.x & 3;                  // 0..3
  const int i  = iq * 4 + (threadIdx.x >> 6);     // 0..1023
  float wreg[32];
  {
    const float4* wp = (const float4*)(W_c + (size_t)i * 2048) + lane * 8;
#pragma unroll
    for (int c = 0; c < 8; ++c) {
      const float4 f = wp[c];
      wreg[c * 4 + 0] = f.x; wreg[c * 4 + 1] = f.y;
      wreg[c * 4 + 2] = f.z; wreg[c * 4 + 3] = f.w;
    }
  }
  const float bc = b_c[i];
  const int jcol = lane * 32;
  const float* xbase = (jcol < kH) ? (rnn + jcol) : (ctx + (jcol - kH));
  for (int b = bq * 16; b < bq * 16 + 16; ++b) {
    const float* xr = xbase + (size_t)b * kH;
    float acc = 0.f;
#pragma unroll
    for (int c = 0; c < 8; ++c) {
      const float4 x = *(const float4*)(xr + c * 4);
      acc += wreg[c * 4 + 0] * x.x + wreg[c * 4 + 1] * x.y +
             wreg[c * 4 + 2] * x.z + wreg[c * 4 + 3] * x.w;
    }
    acc = warp_sum(acc);
    if (lane == 0) coT[(size_t)i * kB + b] = tanhf(acc + bc);
  }
}

// ---------------- out[b][v] = coT[:,b] . W_out[v] + b_out[v] ----------------
// 625 blocks x 256 threads; stage 16 W_out rows (64 KB) in LDS with 16
// outstanding coalesced float4 loads/thread; lane=b; broadcast LDS W reads.
__global__ __launch_bounds__(256) void k_out(const float* __restrict__ coT,
    const float* __restrict__ W_out, const float* __restrict__ b_out,
    float* __restrict__ out) {
  __shared__ float wlds[16 * kH];  // 64 KB: 16 rows of W_out
  const int v0 = blockIdx.x * 16;
  {
    const float4* src = (const float4*)(W_out + (size_t)v0 * kH);
    float4 tmp[16];
#pragma unroll
    for (int c = 0; c < 16; ++c) tmp[c] = src[threadIdx.x + 256 * c];
    float4* dst = (float4*)wlds;
#pragma unroll
    for (int c = 0; c < 16; ++c) dst[threadIdx.x + 256 * c] = tmp[c];
  }
  __syncthreads();

  const int lane = threadIdx.x & 63;   // = b
  const int w    = threadIdx.x >> 6;   // wave: v-rows 4w..4w+3
  float acc[4] = {0.f, 0.f, 0.f, 0.f};
#pragma unroll 2
  for (int h = 0; h < kH; h += 4) {
    const float x0 = coT[(size_t)(h + 0) * kB + lane];
    const float x1 = coT[(size_t)(h + 1) * kB + lane];
    const float x2 = coT[(size_t)(h + 2) * kB + lane];
    const float x3 = coT[(size_t)(h + 3) * kB + lane];
#pragma unroll
    for (int vi = 0; vi < 4; ++vi) {
      const float4 wq = *(const float4*)&wlds[(w * 4 + vi) * kH + h];
      acc[vi] += wq.x * x0 + wq.y * x1 + wq.z * x2 + wq.w * x3;
    }
  }
  const float4 bq = *(const float4*)(b_out + v0 + w * 4);
  float4 r;
  r.x = acc[0] + bq.x; r.y = acc[1] + bq.y;
  r.z = acc[2] + bq.z; r.w = acc[3] + bq.w;
  *(float4*)&out[(size_t)lane * kV + v0 + w * 4] = r;
}

// ---------------- launcher ----------------
extern "C" void kernel_launch(void* const* d_in, const int* in_sizes, int n_in,
                              void* d_out, int out_size, void* d_ws,
                              size_t ws_size, hipStream_t stream) {
  const int*   seq    = (const int*)  d_in[0];
  const float* h0     = (const float*)d_in[1];
  const float* enc    = (const float*)d_in[2];
  const float* emb    = (const float*)d_in[3];
  const float* W_ih   = (const float*)d_in[4];
  const float* W_hh   = (const float*)d_in[5];
  const float* b_ih   = (const float*)d_in[6];
  const float* b_hh   = (const float*)d_in[7];
  const float* W_attn = (const float*)d_in[8];
  // d_in[9] = b_attn: drops out of softmax (shift invariance)
  const float* v_attn = (const float*)d_in[10];
  const float* W_conc = (const float*)d_in[11];
  const float* b_conc = (const float*)d_in[12];
  const float* W_outp = (const float*)d_in[13];
  const float* b_outp = (const float*)d_in[14];

  float* out      = (float*)d_out;           // (B,V) = 640000
  float* out_hid  = out + 640000;            // (1,1,H) = 1024
  float* out_attn = out + 641024;            // (B,1,S) = 16384

  float* ws = (float*)d_ws;
  float* GI   = ws;                      // 64*3072   = 196608
  float* RNN  = ws + 196608;             // 64*1024   =  65536
  unsigned long long* STEP =
      (unsigned long long*)(ws + 262144);  // 64*1024 u64 = 131072 floats
  float* W2H  = ws + 393216;             // 1024
  float* SC   = ws + 394240;             // 64*256    =  16384
  float* CTX  = ws + 672768;             // 64*1024   =  65536
  float* COT  = ws + 738304;             // 1024*64   =  65536 (end 803840 floats)

  k_gi<<<768, 256, 0, stream>>>(seq, emb, W_ih, b_ih, GI);
  k_gru<<<256, 256, 0, stream>>>(h0, W_hh, b_hh, GI, RNN, STEP);
  k_w2h<<<256, 256, 0, stream>>>(W_attn, v_attn, W2H);
  k_scores<<<4096, 256, 0, stream>>>(enc, W2H, SC);
  k_ctx2<<<64, 1024, 0, stream>>>(SC, enc, RNN, out_attn, CTX, out_hid);
  k_concat<<<1024, 256, 0, stream>>>(RNN, CTX, W_conc, b_conc, COT);
  k_out<<<625, 256, 0, stream>>>(COT, W_outp, b_outp, out);
}